// Round 1
// baseline (1161.027 us; speedup 1.0000x reference)
//
#include <hip/hip_runtime.h>

#define NB 2048
#define NT 1024

// sigmoid via native exp2 + rcp (v_exp_f32, v_rcp_f32)
__device__ __forceinline__ float sig_fast(float x) {
    return __builtin_amdgcn_rcpf(1.0f + exp2f(-1.4426950408889634f * x));
}
// tanh(x) = 2*sigmoid(2x) - 1
__device__ __forceinline__ float tanh_fast(float x) {
    return fmaf(2.0f, __builtin_amdgcn_rcpf(1.0f + exp2f(-2.8853900817779268f * x)), -1.0f);
}

__global__ void zero_loss_kernel(float* out) { out[0] = 0.0f; }

__global__ __launch_bounds__(64, 2)
void decoder_lstm_kernel(const float* __restrict__ seq,    // (B,T,1)
                         const float* __restrict__ z,      // (B,32)
                         const float* __restrict__ w_ih0,  // (128,1)
                         const float* __restrict__ w_hh0,  // (128,32)
                         const float* __restrict__ b_ih0,  // (128,)
                         const float* __restrict__ b_hh0,  // (128,)
                         const float* __restrict__ w_ih1,  // (128,32)
                         const float* __restrict__ w_hh1,  // (128,32)
                         const float* __restrict__ b_ih1,  // (128,)
                         const float* __restrict__ b_hh1,  // (128,)
                         const float* __restrict__ w_out,  // (1,32)
                         const float* __restrict__ b_out,  // (1,)
                         float* __restrict__ out)          // [0]=loss, [1..]=recovered (B,T,1)
{
    const int b  = blockIdx.x;     // batch element, one wave per block
    const int l  = threadIdx.x;    // 0..63
    const int lo = l & 31;

    __shared__ float sh_h0[32];
    __shared__ float sh_h1[32];

    // Each lane owns gate rows rA = l and rB = l + 64.
    // PyTorch gate order i,f,g,o (32 each):
    //   lane<32 : rA = i[lo], rB = g[lo]
    //   lane>=32: rA = f[lo], rB = o[lo]
    const int rA = l;
    const int rB = l + 64;

    float wih0A  = w_ih0[rA];
    float wih0B  = w_ih0[rB];
    float bias0A = b_ih0[rA] + b_hh0[rA];
    float bias0B = b_ih0[rB] + b_hh0[rB];
    float bias1A = b_ih1[rA] + b_hh1[rA];
    float bias1B = b_ih1[rB] + b_hh1[rB];

    // Register-resident weight rows: 6 x 32 = 192 VGPRs. Deliberate — LDS
    // bandwidth (128 B/cyc/CU) cannot feed 8 waves of fp32 FMA streams.
    float whh0A[32], whh0B[32], wih1A[32], wih1B[32], whh1A[32], whh1B[32];
#pragma unroll
    for (int k = 0; k < 32; k += 4) {
        float4 r;
        r = *(const float4*)&w_hh0[rA * 32 + k]; whh0A[k]=r.x; whh0A[k+1]=r.y; whh0A[k+2]=r.z; whh0A[k+3]=r.w;
        r = *(const float4*)&w_hh0[rB * 32 + k]; whh0B[k]=r.x; whh0B[k+1]=r.y; whh0B[k+2]=r.z; whh0B[k+3]=r.w;
        r = *(const float4*)&w_ih1[rA * 32 + k]; wih1A[k]=r.x; wih1A[k+1]=r.y; wih1A[k+2]=r.z; wih1A[k+3]=r.w;
        r = *(const float4*)&w_ih1[rB * 32 + k]; wih1B[k]=r.x; wih1B[k+1]=r.y; wih1B[k+2]=r.z; wih1B[k+3]=r.w;
        r = *(const float4*)&w_hh1[rA * 32 + k]; whh1A[k]=r.x; whh1A[k+1]=r.y; whh1A[k+2]=r.z; whh1A[k+3]=r.w;
        r = *(const float4*)&w_hh1[rB * 32 + k]; whh1B[k]=r.x; whh1B[k+1]=r.y; whh1B[k+2]=r.z; whh1B[k+3]=r.w;
    }

    float wOut = (l < 32) ? w_out[lo] : 0.0f;   // 0 on upper lanes -> clean reduction
    float bOut = b_out[0];

    // init: h0 = c0 = h1 = c1 = z, pred = 0
    float zv = z[(size_t)b * 32 + lo];
    if (l < 32) { sh_h0[l] = zv; sh_h1[l] = zv; }
    float cc0 = zv;   // c0[lo], valid on lanes 0..31
    float cc1 = zv;   // c1[lo]
    float pred = 0.0f;
    float sse  = 0.0f;

    const float* seq_b = seq + (size_t)b * NT;
    float* out_b = out + 1 + (size_t)b * NT;

    __syncthreads();

    for (int t = 0; t < NT; ++t) {
        float x = seq_b[t];   // issued early, consumed at loop end

        // ---------------- cell 0: gates = pred*w_ih0 + h0 @ w_hh0^T + b0
        float a0 = fmaf(pred, wih0A, bias0A), a1 = 0.0f;
        float b0 = fmaf(pred, wih0B, bias0B), b1 = 0.0f;
#pragma unroll
        for (int k = 0; k < 32; k += 4) {
            float4 h4 = *(const float4*)&sh_h0[k];   // broadcast read
            a0 = fmaf(whh0A[k+0], h4.x, a0);  b0 = fmaf(whh0B[k+0], h4.x, b0);
            a1 = fmaf(whh0A[k+1], h4.y, a1);  b1 = fmaf(whh0B[k+1], h4.y, b1);
            a0 = fmaf(whh0A[k+2], h4.z, a0);  b0 = fmaf(whh0B[k+2], h4.z, b0);
            a1 = fmaf(whh0A[k+3], h4.w, a1);  b1 = fmaf(whh0B[k+3], h4.w, b1);
        }
        float gA = a0 + a1;   // lane<32: i ; lane>=32: f
        float gB = b0 + b1;   // lane<32: g ; lane>=32: o

        float sA   = sig_fast(gA);                       // sig(i) / sig(f)
        float argB = (l < 32) ? (gB + gB) : gB;          // tanh via 2*sig(2x)-1
        float sB   = sig_fast(argB);
        float vB   = (l < 32) ? fmaf(2.0f, sB, -1.0f) : sB;  // tanh(g) / sig(o)

        float fOrI = __shfl_xor(sA, 32);   // lane<32 receives sig(f)
        float oOrG = __shfl_xor(vB, 32);   // lane<32 receives sig(o)
        cc0 = fmaf(fOrI, cc0, sA * vB);          // c0 = f*c0 + i*tanh(g)   (lanes<32)
        float h0n = oOrG * tanh_fast(cc0);       // h0 = o*tanh(c0)         (lanes<32)
        if (l < 32) sh_h0[l] = h0n;
        __syncthreads();

        // ---------------- cell 1: gates = h0n @ w_ih1^T + h1 @ w_hh1^T + b1
        float cA0 = bias1A, cA1 = 0.0f;
        float cB0 = bias1B, cB1 = 0.0f;
#pragma unroll
        for (int k = 0; k < 32; k += 4) {
            float4 u = *(const float4*)&sh_h0[k];   // h0n
            float4 v = *(const float4*)&sh_h1[k];   // h1
            cA0 = fmaf(wih1A[k+0], u.x, cA0);  cB0 = fmaf(wih1B[k+0], u.x, cB0);
            cA1 = fmaf(whh1A[k+0], v.x, cA1);  cB1 = fmaf(whh1B[k+0], v.x, cB1);
            cA0 = fmaf(wih1A[k+1], u.y, cA0);  cB0 = fmaf(wih1B[k+1], u.y, cB0);
            cA1 = fmaf(whh1A[k+1], v.y, cA1);  cB1 = fmaf(whh1B[k+1], v.y, cB1);
            cA0 = fmaf(wih1A[k+2], u.z, cA0);  cB0 = fmaf(wih1B[k+2], u.z, cB0);
            cA1 = fmaf(whh1A[k+2], v.z, cA1);  cB1 = fmaf(whh1B[k+2], v.z, cB1);
            cA0 = fmaf(wih1A[k+3], u.w, cA0);  cB0 = fmaf(wih1B[k+3], u.w, cB0);
            cA1 = fmaf(whh1A[k+3], v.w, cA1);  cB1 = fmaf(whh1B[k+3], v.w, cB1);
        }
        float g1A = cA0 + cA1;
        float g1B = cB0 + cB1;

        float s1A   = sig_fast(g1A);
        float arg1B = (l < 32) ? (g1B + g1B) : g1B;
        float s1B   = sig_fast(arg1B);
        float v1B   = (l < 32) ? fmaf(2.0f, s1B, -1.0f) : s1B;

        float f1 = __shfl_xor(s1A, 32);
        float o1 = __shfl_xor(v1B, 32);
        cc1 = fmaf(f1, cc1, s1A * v1B);
        float h1n = o1 * tanh_fast(cc1);          // lanes<32 valid

        // pred = b_out + sum_k w_out[k]*h1n[k]  (upper lanes contribute 0 via wOut=0)
        float term = wOut * h1n;
        term += __shfl_xor(term, 1);
        term += __shfl_xor(term, 2);
        term += __shfl_xor(term, 4);
        term += __shfl_xor(term, 8);
        term += __shfl_xor(term, 16);
        term += __shfl_xor(term, 32);
        pred = term + bOut;

        if (l < 32) sh_h1[l] = h1n;
        __syncthreads();

        out_b[t] = pred;              // all lanes same value/address -> 1 transaction
        float d = x - pred;
        sse = fmaf(d, d, sse);        // uniform across lanes
    }

    if (l == 0) {
        // 1/(2048*1024) = 2^-21, exact in fp32
        atomicAdd(out, sse * (1.0f / ((float)NB * (float)NT)));
    }
}

extern "C" void kernel_launch(void* const* d_in, const int* in_sizes, int n_in,
                              void* d_out, int out_size, void* d_ws, size_t ws_size,
                              hipStream_t stream) {
    const float* seq   = (const float*)d_in[0];
    const float* z     = (const float*)d_in[1];
    // d_in[2] = lengths (unused; reference ignores it)
    const float* w_ih0 = (const float*)d_in[3];
    const float* w_hh0 = (const float*)d_in[4];
    const float* b_ih0 = (const float*)d_in[5];
    const float* b_hh0 = (const float*)d_in[6];
    const float* w_ih1 = (const float*)d_in[7];
    const float* w_hh1 = (const float*)d_in[8];
    const float* b_ih1 = (const float*)d_in[9];
    const float* b_hh1 = (const float*)d_in[10];
    const float* w_out = (const float*)d_in[11];
    const float* b_out = (const float*)d_in[12];
    float* out = (float*)d_out;

    hipLaunchKernelGGL(zero_loss_kernel, dim3(1), dim3(1), 0, stream, out);
    hipLaunchKernelGGL(decoder_lstm_kernel, dim3(NB), dim3(64), 0, stream,
                       seq, z, w_ih0, w_hh0, b_ih0, b_hh0,
                       w_ih1, w_hh1, b_ih1, b_hh1, w_out, b_out, out);
}